// Round 1
// baseline (1029.554 us; speedup 1.0000x reference)
//
#include <hip/hip_runtime.h>
#include <stdint.h>

#define T_SEQ 2048
#define HID 7168
#define NH 32
#define DN 128
#define DR 64
#define DQK 192
#define DV 128
#define QL 1536
#define KVL 512
#define LATD 576
#define QD 6144
#define KVD 8192
#define WOK 4096

typedef unsigned short u16;
typedef __bf16 bf16x8 __attribute__((ext_vector_type(8)));
typedef float f32x4 __attribute__((ext_vector_type(4)));

__device__ __forceinline__ u16 f2bf(float f) {
  union { float f; unsigned u; } v; v.f = f;
  unsigned r = v.u + 0x7FFFu + ((v.u >> 16) & 1u);
  return (u16)(r >> 16);
}

__device__ __forceinline__ void gl2lds16(const void* g, void* l) {
  __builtin_amdgcn_global_load_lds((const __attribute__((address_space(1))) void*)g,
                                   (__attribute__((address_space(3))) void*)l, 16, 0, 0);
}

__device__ __forceinline__ f32x4 mfma16(bf16x8 a, bf16x8 b, f32x4 c) {
  return __builtin_amdgcn_mfma_f32_16x16x32_bf16(a, b, c, 0, 0, 0);
}

// ---------------- elementwise f32 -> bf16 ----------------
__global__ __launch_bounds__(256) void k_cvt_bf16(const float* __restrict__ in,
                                                  u16* __restrict__ out, long long n) {
  long long i = ((long long)blockIdx.x * 256 + threadIdx.x) * 8;
  if (i >= n) return;
  const float4* p = (const float4*)(in + i);
  float4 a = p[0], b = p[1];
  union { uint4 v; u16 s[8]; } o;
  o.s[0]=f2bf(a.x); o.s[1]=f2bf(a.y); o.s[2]=f2bf(a.z); o.s[3]=f2bf(a.w);
  o.s[4]=f2bf(b.x); o.s[5]=f2bf(b.y); o.s[6]=f2bf(b.z); o.s[7]=f2bf(b.w);
  *(uint4*)(out + i) = o.v;
}

// ---------------- transpose + convert: in[R][C] f32 -> out[C][R] bf16 ----------------
__global__ __launch_bounds__(256) void k_transpose_bf16(const float* __restrict__ in,
                                                        u16* __restrict__ out, int R, int C) {
  __shared__ float tile[64][65];
  int c0 = blockIdx.x * 64, r0 = blockIdx.y * 64;
  int tx = threadIdx.x & 15, ty = threadIdx.x >> 4;
  #pragma unroll
  for (int i = 0; i < 4; i++) {
    int r = ty + i * 16;
    float4 v = *(const float4*)(in + (size_t)(r0 + r) * C + c0 + tx * 4);
    tile[r][tx*4+0] = v.x; tile[r][tx*4+1] = v.y; tile[r][tx*4+2] = v.z; tile[r][tx*4+3] = v.w;
  }
  __syncthreads();
  #pragma unroll
  for (int i = 0; i < 4; i++) {
    int oc = ty + i * 16;
    union { uint2 v; u16 s[4]; } o;
    #pragma unroll
    for (int j = 0; j < 4; j++) o.s[j] = f2bf(tile[tx*4+j][oc]);
    *(uint2*)(out + (size_t)(c0 + oc) * R + r0 + tx * 4) = o.v;
  }
}

// ---------------- rmsnorm row-wise: f32 in (ld=ldin), bf16 out [n] ----------------
__global__ __launch_bounds__(256) void k_rmsnorm_bf16(const float* __restrict__ x,
                                                      const float* __restrict__ w,
                                                      u16* __restrict__ out, int n, int ldin) {
  int row = blockIdx.x;
  const float* xr = x + (size_t)row * ldin;
  u16* orow = out + (size_t)row * n;
  float ss = 0.f;
  for (int i = threadIdx.x * 4; i < n; i += 1024) {
    float4 v = *(const float4*)(xr + i);
    ss += v.x*v.x + v.y*v.y + v.z*v.z + v.w*v.w;
  }
  #pragma unroll
  for (int off = 32; off > 0; off >>= 1) ss += __shfl_xor(ss, off);
  __shared__ float red[4];
  if ((threadIdx.x & 63) == 0) red[threadIdx.x >> 6] = ss;
  __syncthreads();
  float tot = red[0] + red[1] + red[2] + red[3];
  float rstd = rsqrtf(tot / (float)n + 1e-6f);
  for (int i = threadIdx.x * 4; i < n; i += 1024) {
    float4 v = *(const float4*)(xr + i);
    float4 g = *(const float4*)(w + i);
    union { uint2 u; u16 s[4]; } o;
    o.s[0]=f2bf(v.x*rstd*g.x); o.s[1]=f2bf(v.y*rstd*g.y);
    o.s[2]=f2bf(v.z*rstd*g.z); o.s[3]=f2bf(v.w*rstd*g.w);
    *(uint2*)(orow + i) = o.u;
  }
}

// ---------------- GEMM: C[M][N] f32 = A[M][K] bf16 @ Bt[N][K]^T (m97 structure) ----------------
__global__ __launch_bounds__(256) void k_gemm_bt(const u16* __restrict__ A,
                                                 const u16* __restrict__ Bt,
                                                 float* __restrict__ C,
                                                 int M, int N, int K) {
  __shared__ __attribute__((aligned(16))) u16 As[128 * 32];
  __shared__ __attribute__((aligned(16))) u16 Bs[128 * 32];
  int m0 = blockIdx.y * 128, n0 = blockIdx.x * 128;
  int tid = threadIdx.x;
  int w = tid >> 6, lane = tid & 63, l16 = lane & 15, lh = lane >> 4;
  int wr = (w >> 1) * 64, wc = (w & 1) * 64;
  f32x4 zero = {0.f, 0.f, 0.f, 0.f};
  f32x4 acc[4][4];
  #pragma unroll
  for (int i = 0; i < 4; i++)
    #pragma unroll
    for (int j = 0; j < 4; j++) acc[i][j] = zero;
  int ra = tid >> 2, ca = (tid & 3) * 8;
  const u16* a0 = A + (size_t)(m0 + ra) * K + ca;
  const u16* a1 = A + (size_t)(m0 + ra + 64) * K + ca;
  int rb0 = n0 + ra;      rb0 = rb0 < N ? rb0 : N - 1;
  int rb1 = n0 + ra + 64; rb1 = rb1 < N ? rb1 : N - 1;
  const u16* b0 = Bt + (size_t)rb0 * K + ca;
  const u16* b1 = Bt + (size_t)rb1 * K + ca;
  for (int k0 = 0; k0 < K; k0 += 32) {
    gl2lds16(a0 + k0, &As[tid * 8]);
    gl2lds16(a1 + k0, &As[2048 + tid * 8]);
    gl2lds16(b0 + k0, &Bs[tid * 8]);
    gl2lds16(b1 + k0, &Bs[2048 + tid * 8]);
    __syncthreads();
    bf16x8 af[4], bv[4];
    #pragma unroll
    for (int i = 0; i < 4; i++) af[i] = *(const bf16x8*)&As[(wr + i * 16 + l16) * 32 + lh * 8];
    #pragma unroll
    for (int j = 0; j < 4; j++) bv[j] = *(const bf16x8*)&Bs[(wc + j * 16 + l16) * 32 + lh * 8];
    #pragma unroll
    for (int i = 0; i < 4; i++)
      #pragma unroll
      for (int j = 0; j < 4; j++)
        acc[i][j] = mfma16(af[i], bv[j], acc[i][j]);
    __syncthreads();
  }
  #pragma unroll
  for (int i = 0; i < 4; i++) {
    #pragma unroll
    for (int j = 0; j < 4; j++) {
      int col = n0 + wc + j * 16 + l16;
      if (col < N) {
        #pragma unroll
        for (int r = 0; r < 4; r++) {
          int row = m0 + wr + i * 16 + lh * 4 + r;
          C[(size_t)row * N + col] = acc[i][j][r];
        }
      }
    }
  }
}

// ---------------- build Q: qfull[T][6144] f32 -> Qc[NH][T][192] bf16 (rope + scale) ----------------
__global__ __launch_bounds__(256) void k_build_q(const float* __restrict__ qf,
                                                 const int* __restrict__ pos,
                                                 u16* __restrict__ Qc) {
  int t = blockIdx.x;
  __shared__ float cs[32], sn[32];
  if (threadIdx.x < 32) {
    float inv = expf(-9.2103403719761836f * (float)threadIdx.x / 32.f);
    float ang = (float)pos[t] * inv;
    cs[threadIdx.x] = cosf(ang);
    sn[threadIdx.x] = sinf(ang);
  }
  __syncthreads();
  const float scale = 0.07216878364870322f;  // 192^-0.5
  const float* qrow = qf + (size_t)t * QD;
  for (int e = threadIdx.x; e < QD; e += 256) {
    int h = e / 192, d = e - h * 192;
    float v;
    if (d < DN) {
      v = qrow[e];
    } else {
      int dr = d - DN, i = dr >> 1;
      float x1 = qrow[h * 192 + DN + 2 * i], x2 = qrow[h * 192 + DN + 2 * i + 1];
      v = (dr & 1) ? (x1 * sn[i] + x2 * cs[i]) : (x1 * cs[i] - x2 * sn[i]);
    }
    Qc[((size_t)h * T_SEQ + t) * DQK + d] = f2bf(v * scale);
  }
}

// ---------------- build K: kvfull[T][8192] + latent rope -> Kc[NH][T][192] bf16 ----------------
__global__ __launch_bounds__(256) void k_build_k(const float* __restrict__ kvf,
                                                 const float* __restrict__ lat,
                                                 const int* __restrict__ pos,
                                                 u16* __restrict__ Kc) {
  int t = blockIdx.x;
  __shared__ float kro[64];
  if (threadIdx.x < 32) {
    int i = threadIdx.x;
    float inv = expf(-9.2103403719761836f * (float)i / 32.f);
    float ang = (float)pos[t] * inv;
    float c = cosf(ang), s = sinf(ang);
    float x1 = lat[(size_t)t * LATD + KVL + 2 * i];
    float x2 = lat[(size_t)t * LATD + KVL + 2 * i + 1];
    kro[2 * i]     = x1 * c - x2 * s;
    kro[2 * i + 1] = x1 * s + x2 * c;
  }
  __syncthreads();
  const float* krow = kvf + (size_t)t * KVD;
  for (int e = threadIdx.x; e < NH * DQK; e += 256) {
    int h = e / 192, d = e - h * 192;
    float v = (d < DN) ? krow[h * 256 + d] : kro[d - DN];
    Kc[((size_t)h * T_SEQ + t) * DQK + d] = f2bf(v);
  }
}

// ---------------- build Vt: kvfull[T][8192] (cols h*256+128..255) -> Vt[NH][128][T] bf16 ----------------
__global__ __launch_bounds__(256) void k_build_vt(const float* __restrict__ kvf,
                                                  u16* __restrict__ Vt) {
  __shared__ float tile[64][65];
  int t0 = blockIdx.x * 64, d0 = blockIdx.y * 64, h = blockIdx.z;
  int tx = threadIdx.x & 15, ty = threadIdx.x >> 4;
  #pragma unroll
  for (int i = 0; i < 4; i++) {
    int r = ty + i * 16;
    float4 v = *(const float4*)(kvf + (size_t)(t0 + r) * KVD + h * 256 + DN + d0 + tx * 4);
    tile[r][tx*4+0] = v.x; tile[r][tx*4+1] = v.y; tile[r][tx*4+2] = v.z; tile[r][tx*4+3] = v.w;
  }
  __syncthreads();
  #pragma unroll
  for (int i = 0; i < 4; i++) {
    int od = ty + i * 16;
    union { uint2 v; u16 s[4]; } o;
    #pragma unroll
    for (int j = 0; j < 4; j++) o.s[j] = f2bf(tile[tx*4+j][od]);
    *(uint2*)(Vt + ((size_t)h * DV + d0 + od) * T_SEQ + t0 + tx * 4) = o.v;
  }
}

// ---------------- flash attention: Qc,Kc [NH][T][192], Vt [NH][128][T] -> attn [T][4096] bf16 ----------------
__global__ __launch_bounds__(256) void k_mla_attn(const u16* __restrict__ Qc,
                                                  const u16* __restrict__ Kc,
                                                  const u16* __restrict__ Vt,
                                                  u16* __restrict__ attn) {
  int qt = blockIdx.x, h = blockIdx.y;
  __shared__ __attribute__((aligned(16))) u16 Qs[64 * 192];
  __shared__ __attribute__((aligned(16))) u16 Ks[64 * 192];
  __shared__ __attribute__((aligned(16))) u16 Vs[128 * 64];
  __shared__ __attribute__((aligned(16))) u16 Ps[64 * 64];
  int tid = threadIdx.x, w = tid >> 6, lane = tid & 63, l16 = lane & 15, lh = lane >> 4;

  const u16* Qg = Qc + ((size_t)h * T_SEQ + (size_t)qt * 64) * DQK;
  #pragma unroll
  for (int i = 0; i < 6; i++) { int e = tid * 8 + i * 2048; gl2lds16(Qg + e, &Qs[e]); }

  f32x4 zero = {0.f, 0.f, 0.f, 0.f};
  f32x4 accO[8];
  #pragma unroll
  for (int i = 0; i < 8; i++) accO[i] = zero;
  float m[4]    = {-3e38f, -3e38f, -3e38f, -3e38f};
  float lsum[4] = {0.f, 0.f, 0.f, 0.f};

  for (int kt = 0; kt <= qt; ++kt) {
    const u16* Kg = Kc + ((size_t)h * T_SEQ + (size_t)kt * 64) * DQK;
    #pragma unroll
    for (int i = 0; i < 6; i++) { int e = tid * 8 + i * 2048; gl2lds16(Kg + e, &Ks[e]); }
    const u16* Vg = Vt + (size_t)h * DV * T_SEQ + (size_t)kt * 64;
    #pragma unroll
    for (int i = 0; i < 4; i++) {
      int e = tid * 8 + i * 2048;
      gl2lds16(Vg + (size_t)(e >> 6) * T_SEQ + (e & 63), &Vs[e]);
    }
    __syncthreads();

    f32x4 sf[4];
    #pragma unroll
    for (int j = 0; j < 4; j++) sf[j] = zero;
    #pragma unroll
    for (int kf = 0; kf < 6; ++kf) {
      bf16x8 aq = *(const bf16x8*)&Qs[(w * 16 + l16) * DQK + kf * 32 + lh * 8];
      #pragma unroll
      for (int j = 0; j < 4; ++j) {
        bf16x8 bk = *(const bf16x8*)&Ks[(j * 16 + l16) * DQK + kf * 32 + lh * 8];
        sf[j] = mfma16(aq, bk, sf[j]);
      }
    }
    bool diag = (kt == qt);
    #pragma unroll
    for (int rr = 0; rr < 4; ++rr) {
      int qrow = qt * 64 + w * 16 + lh * 4 + rr;
      float rowm = -3e38f;
      #pragma unroll
      for (int j = 0; j < 4; ++j) {
        float s = sf[j][rr];
        if (diag && (kt * 64 + j * 16 + l16) > qrow) s = -3e38f;
        sf[j][rr] = s;
        rowm = fmaxf(rowm, s);
      }
      rowm = fmaxf(rowm, __shfl_xor(rowm, 1));
      rowm = fmaxf(rowm, __shfl_xor(rowm, 2));
      rowm = fmaxf(rowm, __shfl_xor(rowm, 4));
      rowm = fmaxf(rowm, __shfl_xor(rowm, 8));
      float mnew = fmaxf(m[rr], rowm);
      float sc = __expf(m[rr] - mnew);
      float pj[4];
      float ps = 0.f;
      #pragma unroll
      for (int j = 0; j < 4; ++j) { pj[j] = __expf(sf[j][rr] - mnew); ps += pj[j]; }
      ps += __shfl_xor(ps, 1); ps += __shfl_xor(ps, 2);
      ps += __shfl_xor(ps, 4); ps += __shfl_xor(ps, 8);
      lsum[rr] = lsum[rr] * sc + ps;
      m[rr] = mnew;
      #pragma unroll
      for (int of = 0; of < 8; ++of) accO[of][rr] *= sc;
      #pragma unroll
      for (int j = 0; j < 4; ++j)
        Ps[(w * 16 + lh * 4 + rr) * 64 + j * 16 + l16] = f2bf(pj[j]);
    }
    // PV: wave reads only its own Ps rows (written by same wave)
    #pragma unroll
    for (int kf = 0; kf < 2; ++kf) {
      bf16x8 ap = *(const bf16x8*)&Ps[(w * 16 + l16) * 64 + kf * 32 + lh * 8];
      #pragma unroll
      for (int of = 0; of < 8; ++of) {
        bf16x8 bvv = *(const bf16x8*)&Vs[(of * 16 + l16) * 64 + kf * 32 + lh * 8];
        accO[of] = mfma16(ap, bvv, accO[of]);
      }
    }
    __syncthreads();
  }
  #pragma unroll
  for (int rr = 0; rr < 4; ++rr) {
    float inv = 1.f / lsum[rr];
    int t = qt * 64 + w * 16 + lh * 4 + rr;
    #pragma unroll
    for (int of = 0; of < 8; ++of)
      attn[(size_t)t * WOK + h * DV + of * 16 + l16] = f2bf(accO[of][rr] * inv);
  }
}

extern "C" void kernel_launch(void* const* d_in, const int* in_sizes, int n_in,
                              void* d_out, int out_size, void* d_ws, size_t ws_size,
                              hipStream_t stream) {
  const float* hidden     = (const float*)d_in[0];
  const int*   positions  = (const int*)d_in[1];
  const float* wq_a       = (const float*)d_in[2];
  const float* q_a_ln_w   = (const float*)d_in[3];
  const float* wq_b       = (const float*)d_in[4];
  const float* wkv_a      = (const float*)d_in[5];
  const float* kv_a_ln_w  = (const float*)d_in[6];
  const float* wkv_b      = (const float*)d_in[7];
  const float* wo         = (const float*)d_in[8];
  float* out = (float*)d_out;

  char* p = (char*)d_ws;
  size_t off = 0;
  auto alloc = [&](size_t bytes) -> void* {
    void* r = p + off;
    off += (bytes + 255) & ~(size_t)255;
    return r;
  };
  u16*   h_bf = (u16*)  alloc((size_t)T_SEQ * HID * 2);       // hidden bf16
  u16*   wbuf = (u16*)  alloc((size_t)HID * WOK * 2);         // shared transposed-weight buffer (max = woT)
  float* big  = (float*)alloc((size_t)T_SEQ * KVD * 4);       // kvfull, later qfull
  float* sml  = (float*)alloc((size_t)T_SEQ * QL * 4);        // latent, later q_lat
  u16*   qln  = (u16*)  alloc((size_t)T_SEQ * QL * 2);        // rmsnorm(q_lat) bf16
  u16*   ckv  = (u16*)  alloc((size_t)T_SEQ * KVL * 2);       // rmsnorm(c_kv) bf16
  u16*   Qc   = (u16*)  alloc((size_t)NH * T_SEQ * DQK * 2);  // Q concat, roped, scaled
  u16*   Kc   = (u16*)  alloc((size_t)NH * T_SEQ * DQK * 2);  // K concat
  u16*   Vt   = (u16*)  alloc((size_t)NH * DV * T_SEQ * 2);   // V transposed
  u16*   attn = (u16*)  alloc((size_t)T_SEQ * WOK * 2);       // attention out bf16

  // hidden -> bf16
  k_cvt_bf16<<<(T_SEQ * HID) / (256 * 8), 256, 0, stream>>>(hidden, h_bf, (long long)T_SEQ * HID);

  // ---- KV path ----
  k_transpose_bf16<<<dim3(LATD / 64, HID / 64), 256, 0, stream>>>(wkv_a, wbuf, HID, LATD);
  k_gemm_bt<<<dim3((LATD + 127) / 128, T_SEQ / 128), 256, 0, stream>>>(h_bf, wbuf, sml, T_SEQ, LATD, HID);
  k_rmsnorm_bf16<<<T_SEQ, 256, 0, stream>>>(sml, kv_a_ln_w, ckv, KVL, LATD);
  k_transpose_bf16<<<dim3(KVD / 64, KVL / 64), 256, 0, stream>>>(wkv_b, wbuf, KVL, KVD);
  k_gemm_bt<<<dim3(KVD / 128, T_SEQ / 128), 256, 0, stream>>>(ckv, wbuf, big, T_SEQ, KVD, KVL);
  k_build_k<<<T_SEQ, 256, 0, stream>>>(big, sml, positions, Kc);
  k_build_vt<<<dim3(T_SEQ / 64, 2, NH), 256, 0, stream>>>(big, Vt);

  // ---- Q path (reuses big/sml after KV consumers are done) ----
  k_transpose_bf16<<<dim3(QL / 64, HID / 64), 256, 0, stream>>>(wq_a, wbuf, HID, QL);
  k_gemm_bt<<<dim3(QL / 128, T_SEQ / 128), 256, 0, stream>>>(h_bf, wbuf, sml, T_SEQ, QL, HID);
  k_rmsnorm_bf16<<<T_SEQ, 256, 0, stream>>>(sml, q_a_ln_w, qln, QL, QL);
  k_transpose_bf16<<<dim3(QD / 64, QL / 64), 256, 0, stream>>>(wq_b, wbuf, QL, QD);
  k_gemm_bt<<<dim3(QD / 128, T_SEQ / 128), 256, 0, stream>>>(qln, wbuf, big, T_SEQ, QD, QL);
  k_build_q<<<T_SEQ, 256, 0, stream>>>(big, positions, Qc);

  // ---- attention ----
  k_mla_attn<<<dim3(T_SEQ / 64, NH), 256, 0, stream>>>(Qc, Kc, Vt, attn);

  // ---- output projection ----
  k_transpose_bf16<<<dim3(HID / 64, WOK / 64), 256, 0, stream>>>(wo, wbuf, WOK, HID);
  k_gemm_bt<<<dim3(HID / 128, T_SEQ / 128), 256, 0, stream>>>(attn, wbuf, out, T_SEQ, HID, WOK);
}

// Round 2
// 934.713 us; speedup vs baseline: 1.1015x; 1.1015x over previous
//
#include <hip/hip_runtime.h>
#include <stdint.h>

#define T_SEQ 2048
#define HID 7168
#define NH 32
#define DN 128
#define DR 64
#define DQK 192
#define DV 128
#define QL 1536
#define KVL 512
#define LATD 576
#define QD 6144
#define KVD 8192
#define WOK 4096

typedef unsigned short u16;
typedef __bf16 bf16x8 __attribute__((ext_vector_type(8)));
typedef float f32x4 __attribute__((ext_vector_type(4)));

__device__ __forceinline__ u16 f2bf(float f) {
  union { float f; unsigned u; } v; v.f = f;
  unsigned r = v.u + 0x7FFFu + ((v.u >> 16) & 1u);
  return (u16)(r >> 16);
}
__device__ __forceinline__ float bf2f(u16 s) {
  union { unsigned u; float f; } v; v.u = ((unsigned)s) << 16;
  return v.f;
}

__device__ __forceinline__ void gl2lds16(const void* g, void* l) {
  __builtin_amdgcn_global_load_lds((const __attribute__((address_space(1))) void*)g,
                                   (__attribute__((address_space(3))) void*)l, 16, 0, 0);
}

__device__ __forceinline__ f32x4 mfma16(bf16x8 a, bf16x8 b, f32x4 c) {
  return __builtin_amdgcn_mfma_f32_16x16x32_bf16(a, b, c, 0, 0, 0);
}

// ---------------- elementwise f32 -> bf16 ----------------
__global__ __launch_bounds__(256) void k_cvt_bf16(const float* __restrict__ in,
                                                  u16* __restrict__ out, long long n) {
  long long i = ((long long)blockIdx.x * 256 + threadIdx.x) * 8;
  if (i >= n) return;
  const float4* p = (const float4*)(in + i);
  float4 a = p[0], b = p[1];
  union { uint4 v; u16 s[8]; } o;
  o.s[0]=f2bf(a.x); o.s[1]=f2bf(a.y); o.s[2]=f2bf(a.z); o.s[3]=f2bf(a.w);
  o.s[4]=f2bf(b.x); o.s[5]=f2bf(b.y); o.s[6]=f2bf(b.z); o.s[7]=f2bf(b.w);
  *(uint4*)(out + i) = o.v;
}

// ---------------- transpose + convert + scale: in[R][C] f32 -> out[C][R] bf16 ----------------
__global__ __launch_bounds__(256) void k_transpose_bf16(const float* __restrict__ in,
                                                        u16* __restrict__ out, int R, int C,
                                                        float scale) {
  __shared__ float tile[64][65];
  int c0 = blockIdx.x * 64, r0 = blockIdx.y * 64;
  int tx = threadIdx.x & 15, ty = threadIdx.x >> 4;
  #pragma unroll
  for (int i = 0; i < 4; i++) {
    int r = ty + i * 16;
    float4 v = *(const float4*)(in + (size_t)(r0 + r) * C + c0 + tx * 4);
    tile[r][tx*4+0] = v.x; tile[r][tx*4+1] = v.y; tile[r][tx*4+2] = v.z; tile[r][tx*4+3] = v.w;
  }
  __syncthreads();
  #pragma unroll
  for (int i = 0; i < 4; i++) {
    int oc = ty + i * 16;
    union { uint2 v; u16 s[4]; } o;
    #pragma unroll
    for (int j = 0; j < 4; j++) o.s[j] = f2bf(tile[tx*4+j][oc] * scale);
    *(uint2*)(out + (size_t)(c0 + oc) * R + r0 + tx * 4) = o.v;
  }
}

// ---------------- rmsnorm row-wise: f32 in (ld=ldin), bf16 out [n] ----------------
__global__ __launch_bounds__(256) void k_rmsnorm_bf16(const float* __restrict__ x,
                                                      const float* __restrict__ w,
                                                      u16* __restrict__ out, int n, int ldin) {
  int row = blockIdx.x;
  const float* xr = x + (size_t)row * ldin;
  u16* orow = out + (size_t)row * n;
  float ss = 0.f;
  for (int i = threadIdx.x * 4; i < n; i += 1024) {
    float4 v = *(const float4*)(xr + i);
    ss += v.x*v.x + v.y*v.y + v.z*v.z + v.w*v.w;
  }
  #pragma unroll
  for (int off = 32; off > 0; off >>= 1) ss += __shfl_xor(ss, off);
  __shared__ float red[4];
  if ((threadIdx.x & 63) == 0) red[threadIdx.x >> 6] = ss;
  __syncthreads();
  float tot = red[0] + red[1] + red[2] + red[3];
  float rstd = rsqrtf(tot / (float)n + 1e-6f);
  for (int i = threadIdx.x * 4; i < n; i += 1024) {
    float4 v = *(const float4*)(xr + i);
    float4 g = *(const float4*)(w + i);
    union { uint2 u; u16 s[4]; } o;
    o.s[0]=f2bf(v.x*rstd*g.x); o.s[1]=f2bf(v.y*rstd*g.y);
    o.s[2]=f2bf(v.z*rstd*g.z); o.s[3]=f2bf(v.w*rstd*g.w);
    *(uint2*)(orow + i) = o.u;
  }
}

// ---------------- GEMM: C[M][N] = A[M][K] bf16 @ Bt[N][K]^T (m97 structure) ----------------
// f32-output variant
__global__ __launch_bounds__(256) void k_gemm_bt(const u16* __restrict__ A,
                                                 const u16* __restrict__ Bt,
                                                 float* __restrict__ C,
                                                 int M, int N, int K) {
  __shared__ __attribute__((aligned(16))) u16 As[128 * 32];
  __shared__ __attribute__((aligned(16))) u16 Bs[128 * 32];
  int m0 = blockIdx.y * 128, n0 = blockIdx.x * 128;
  int tid = threadIdx.x;
  int w = tid >> 6, lane = tid & 63, l16 = lane & 15, lh = lane >> 4;
  int wr = (w >> 1) * 64, wc = (w & 1) * 64;
  f32x4 zero = {0.f, 0.f, 0.f, 0.f};
  f32x4 acc[4][4];
  #pragma unroll
  for (int i = 0; i < 4; i++)
    #pragma unroll
    for (int j = 0; j < 4; j++) acc[i][j] = zero;
  int ra = tid >> 2, ca = (tid & 3) * 8;
  const u16* a0 = A + (size_t)(m0 + ra) * K + ca;
  const u16* a1 = A + (size_t)(m0 + ra + 64) * K + ca;
  int rb0 = n0 + ra;      rb0 = rb0 < N ? rb0 : N - 1;
  int rb1 = n0 + ra + 64; rb1 = rb1 < N ? rb1 : N - 1;
  const u16* b0 = Bt + (size_t)rb0 * K + ca;
  const u16* b1 = Bt + (size_t)rb1 * K + ca;
  for (int k0 = 0; k0 < K; k0 += 32) {
    gl2lds16(a0 + k0, &As[tid * 8]);
    gl2lds16(a1 + k0, &As[2048 + tid * 8]);
    gl2lds16(b0 + k0, &Bs[tid * 8]);
    gl2lds16(b1 + k0, &Bs[2048 + tid * 8]);
    __syncthreads();
    bf16x8 af[4], bv[4];
    #pragma unroll
    for (int i = 0; i < 4; i++) af[i] = *(const bf16x8*)&As[(wr + i * 16 + l16) * 32 + lh * 8];
    #pragma unroll
    for (int j = 0; j < 4; j++) bv[j] = *(const bf16x8*)&Bs[(wc + j * 16 + l16) * 32 + lh * 8];
    #pragma unroll
    for (int i = 0; i < 4; i++)
      #pragma unroll
      for (int j = 0; j < 4; j++)
        acc[i][j] = mfma16(af[i], bv[j], acc[i][j]);
    __syncthreads();
  }
  #pragma unroll
  for (int i = 0; i < 4; i++) {
    #pragma unroll
    for (int j = 0; j < 4; j++) {
      int col = n0 + wc + j * 16 + l16;
      if (col < N) {
        #pragma unroll
        for (int r = 0; r < 4; r++) {
          int row = m0 + wr + i * 16 + lh * 4 + r;
          C[(size_t)row * N + col] = acc[i][j][r];
        }
      }
    }
  }
}

// bf16-output variant
__global__ __launch_bounds__(256) void k_gemm_bt_h(const u16* __restrict__ A,
                                                   const u16* __restrict__ Bt,
                                                   u16* __restrict__ C,
                                                   int M, int N, int K) {
  __shared__ __attribute__((aligned(16))) u16 As[128 * 32];
  __shared__ __attribute__((aligned(16))) u16 Bs[128 * 32];
  int m0 = blockIdx.y * 128, n0 = blockIdx.x * 128;
  int tid = threadIdx.x;
  int w = tid >> 6, lane = tid & 63, l16 = lane & 15, lh = lane >> 4;
  int wr = (w >> 1) * 64, wc = (w & 1) * 64;
  f32x4 zero = {0.f, 0.f, 0.f, 0.f};
  f32x4 acc[4][4];
  #pragma unroll
  for (int i = 0; i < 4; i++)
    #pragma unroll
    for (int j = 0; j < 4; j++) acc[i][j] = zero;
  int ra = tid >> 2, ca = (tid & 3) * 8;
  const u16* a0 = A + (size_t)(m0 + ra) * K + ca;
  const u16* a1 = A + (size_t)(m0 + ra + 64) * K + ca;
  const u16* b0 = Bt + (size_t)(n0 + ra) * K + ca;
  const u16* b1 = Bt + (size_t)(n0 + ra + 64) * K + ca;
  for (int k0 = 0; k0 < K; k0 += 32) {
    gl2lds16(a0 + k0, &As[tid * 8]);
    gl2lds16(a1 + k0, &As[2048 + tid * 8]);
    gl2lds16(b0 + k0, &Bs[tid * 8]);
    gl2lds16(b1 + k0, &Bs[2048 + tid * 8]);
    __syncthreads();
    bf16x8 af[4], bv[4];
    #pragma unroll
    for (int i = 0; i < 4; i++) af[i] = *(const bf16x8*)&As[(wr + i * 16 + l16) * 32 + lh * 8];
    #pragma unroll
    for (int j = 0; j < 4; j++) bv[j] = *(const bf16x8*)&Bs[(wc + j * 16 + l16) * 32 + lh * 8];
    #pragma unroll
    for (int i = 0; i < 4; i++)
      #pragma unroll
      for (int j = 0; j < 4; j++)
        acc[i][j] = mfma16(af[i], bv[j], acc[i][j]);
    __syncthreads();
  }
  #pragma unroll
  for (int i = 0; i < 4; i++) {
    #pragma unroll
    for (int j = 0; j < 4; j++) {
      int col = n0 + wc + j * 16 + l16;
      #pragma unroll
      for (int r = 0; r < 4; r++) {
        int row = m0 + wr + i * 16 + lh * 4 + r;
        C[(size_t)row * N + col] = f2bf(acc[i][j][r]);
      }
    }
  }
}

// ---------------- build Q: qfull[T][6144] bf16 (pre-scaled) -> Qc[NH][T][192] bf16 (rope) ----------------
__global__ __launch_bounds__(256) void k_build_q(const u16* __restrict__ qf,
                                                 const int* __restrict__ pos,
                                                 u16* __restrict__ Qc) {
  int t = blockIdx.x;
  __shared__ float cs[32], sn[32];
  if (threadIdx.x < 32) {
    float inv = expf(-9.2103403719761836f * (float)threadIdx.x / 32.f);
    float ang = (float)pos[t] * inv;
    cs[threadIdx.x] = cosf(ang);
    sn[threadIdx.x] = sinf(ang);
  }
  __syncthreads();
  const u16* qrow = qf + (size_t)t * QD;
  for (int e = threadIdx.x; e < QD; e += 256) {
    int h = e / 192, d = e - h * 192;
    u16 outv;
    if (d < DN) {
      outv = qrow[e];
    } else {
      int dr = d - DN, i = dr >> 1;
      float x1 = bf2f(qrow[h * 192 + DN + 2 * i]), x2 = bf2f(qrow[h * 192 + DN + 2 * i + 1]);
      float v = (dr & 1) ? (x1 * sn[i] + x2 * cs[i]) : (x1 * cs[i] - x2 * sn[i]);
      outv = f2bf(v);
    }
    Qc[((size_t)h * T_SEQ + t) * DQK + d] = outv;
  }
}

// ---------------- build K: kvfull[T][8192] bf16 + latent rope -> Kc[NH][T][192] bf16 ----------------
__global__ __launch_bounds__(256) void k_build_k(const u16* __restrict__ kvf,
                                                 const float* __restrict__ lat,
                                                 const int* __restrict__ pos,
                                                 u16* __restrict__ Kc) {
  int t = blockIdx.x;
  __shared__ u16 kro[64];
  if (threadIdx.x < 32) {
    int i = threadIdx.x;
    float inv = expf(-9.2103403719761836f * (float)i / 32.f);
    float ang = (float)pos[t] * inv;
    float c = cosf(ang), s = sinf(ang);
    float x1 = lat[(size_t)t * LATD + KVL + 2 * i];
    float x2 = lat[(size_t)t * LATD + KVL + 2 * i + 1];
    kro[2 * i]     = f2bf(x1 * c - x2 * s);
    kro[2 * i + 1] = f2bf(x1 * s + x2 * c);
  }
  __syncthreads();
  const u16* krow = kvf + (size_t)t * KVD;
  for (int e = threadIdx.x; e < NH * DQK; e += 256) {
    int h = e / 192, d = e - h * 192;
    Kc[((size_t)h * T_SEQ + t) * DQK + d] = (d < DN) ? krow[h * 256 + d] : kro[d - DN];
  }
}

// ---------------- build Vt: kvfull[T][8192] bf16 (cols h*256+128..255) -> Vt[NH][128][T] ----------------
__global__ __launch_bounds__(256) void k_build_vt(const u16* __restrict__ kvf,
                                                  u16* __restrict__ Vt) {
  __shared__ unsigned tile[64][65];
  int t0 = blockIdx.x * 64, d0 = blockIdx.y * 64, h = blockIdx.z;
  int tid = threadIdx.x;
  #pragma unroll
  for (int i = 0; i < 2; i++) {
    int r = (tid >> 3) + i * 32;
    int c = (tid & 7) * 8;
    uint4 v = *(const uint4*)(kvf + (size_t)(t0 + r) * KVD + h * 256 + DN + d0 + c);
    const u16* s = (const u16*)&v;
    #pragma unroll
    for (int j = 0; j < 8; j++) tile[r][c + j] = s[j];
  }
  __syncthreads();
  #pragma unroll
  for (int i = 0; i < 2; i++) {
    int d = (tid >> 3) + i * 32;
    int tb = (tid & 7) * 8;
    union { uint4 v; u16 s[8]; } o;
    #pragma unroll
    for (int j = 0; j < 8; j++) o.s[j] = (u16)tile[tb + j][d];
    *(uint4*)(Vt + ((size_t)h * DV + d0 + d) * T_SEQ + t0 + tb) = o.v;
  }
}

// ---------------- flash attention, XOR-swizzled LDS + Q-hoist ----------------
__global__ __launch_bounds__(256) void k_mla_attn(const u16* __restrict__ Qc,
                                                  const u16* __restrict__ Kc,
                                                  const u16* __restrict__ Vt,
                                                  u16* __restrict__ attn) {
  int qt = blockIdx.x, h = blockIdx.y;
  __shared__ __attribute__((aligned(16))) u16 Ks[64 * 192];   // 24KB, 384B rows, swizzled
  __shared__ __attribute__((aligned(16))) u16 Vs[128 * 64];   // 16KB, 128B rows, swizzled
  __shared__ __attribute__((aligned(16))) u16 Ps[64 * 64];    //  8KB, 128B rows, swizzled
  int tid = threadIdx.x, w = tid >> 6, lane = tid & 63, l16 = lane & 15, lh = lane >> 4;
  int swz = (l16 & 7) << 4;

  // stage Q through Ks (pre-swizzled global source, linear LDS dest), hoist frags
  const char* Qg = (const char*)(Qc + ((size_t)h * T_SEQ + (size_t)qt * 64) * DQK);
  #pragma unroll
  for (int i = 0; i < 6; i++) {
    int L = tid * 16 + i * 4096;
    int row = L / 384;
    gl2lds16(Qg + (L ^ ((row & 7) << 4)), (char*)Ks + L);
  }
  __syncthreads();
  bf16x8 aq[6];
  #pragma unroll
  for (int kf = 0; kf < 6; kf++)
    aq[kf] = *(const bf16x8*)((const char*)Ks + (w * 16 + l16) * 384 + ((kf * 64 + lh * 16) ^ swz));
  __syncthreads();

  f32x4 zero = {0.f, 0.f, 0.f, 0.f};
  f32x4 accO[8];
  #pragma unroll
  for (int i = 0; i < 8; i++) accO[i] = zero;
  float m[4]    = {-3e38f, -3e38f, -3e38f, -3e38f};
  float lsum[4] = {0.f, 0.f, 0.f, 0.f};

  const char* Kb = (const char*)(Kc + (size_t)h * T_SEQ * DQK);
  const char* Vb = (const char*)(Vt + (size_t)h * DV * T_SEQ);

  for (int kt = 0; kt <= qt; ++kt) {
    const char* Kg = Kb + (size_t)kt * 64 * DQK * 2;
    #pragma unroll
    for (int i = 0; i < 6; i++) {
      int L = tid * 16 + i * 4096;
      int row = L / 384;
      gl2lds16(Kg + (L ^ ((row & 7) << 4)), (char*)Ks + L);
    }
    #pragma unroll
    for (int i = 0; i < 4; i++) {
      int L = tid * 16 + i * 4096;
      int row = L >> 7, wb = L & 127;
      gl2lds16(Vb + (size_t)row * (T_SEQ * 2) + (size_t)kt * 128 + (wb ^ ((row & 7) << 4)),
               (char*)Vs + L);
    }
    __syncthreads();

    f32x4 sf[4];
    #pragma unroll
    for (int j = 0; j < 4; j++) sf[j] = zero;
    #pragma unroll
    for (int kf = 0; kf < 6; ++kf) {
      #pragma unroll
      for (int j = 0; j < 4; ++j) {
        bf16x8 bk = *(const bf16x8*)((const char*)Ks + (j * 16 + l16) * 384 +
                                     ((kf * 64 + lh * 16) ^ swz));
        sf[j] = mfma16(aq[kf], bk, sf[j]);
      }
    }
    bool diag = (kt == qt);
    #pragma unroll
    for (int rr = 0; rr < 4; ++rr) {
      int qrow = qt * 64 + w * 16 + lh * 4 + rr;
      float rowm = -3e38f;
      #pragma unroll
      for (int j = 0; j < 4; ++j) {
        float s = sf[j][rr];
        if (diag && (kt * 64 + j * 16 + l16) > qrow) s = -3e38f;
        sf[j][rr] = s;
        rowm = fmaxf(rowm, s);
      }
      rowm = fmaxf(rowm, __shfl_xor(rowm, 1));
      rowm = fmaxf(rowm, __shfl_xor(rowm, 2));
      rowm = fmaxf(rowm, __shfl_xor(rowm, 4));
      rowm = fmaxf(rowm, __shfl_xor(rowm, 8));
      float mnew = fmaxf(m[rr], rowm);
      float sc = __expf(m[rr] - mnew);
      float pj[4];
      float ps = 0.f;
      #pragma unroll
      for (int j = 0; j < 4; ++j) { pj[j] = __expf(sf[j][rr] - mnew); ps += pj[j]; }
      ps += __shfl_xor(ps, 1); ps += __shfl_xor(ps, 2);
      ps += __shfl_xor(ps, 4); ps += __shfl_xor(ps, 8);
      lsum[rr] = lsum[rr] * sc + ps;
      m[rr] = mnew;
      #pragma unroll
      for (int of = 0; of < 8; ++of) accO[of][rr] *= sc;
      int r = w * 16 + lh * 4 + rr;
      int rsw = (r & 7) << 4;
      #pragma unroll
      for (int j = 0; j < 4; ++j)
        *(u16*)((char*)Ps + r * 128 + ((2 * (j * 16 + l16)) ^ rsw)) = f2bf(pj[j]);
    }
    // PV: wave reads only its own Ps rows (written by same wave; in-wave program order)
    #pragma unroll
    for (int kf = 0; kf < 2; ++kf) {
      bf16x8 ap = *(const bf16x8*)((const char*)Ps + (w * 16 + l16) * 128 +
                                   ((kf * 64 + lh * 16) ^ swz));
      #pragma unroll
      for (int of = 0; of < 8; ++of) {
        bf16x8 bvv = *(const bf16x8*)((const char*)Vs + (of * 16 + l16) * 128 +
                                      ((kf * 64 + lh * 16) ^ swz));
        accO[of] = mfma16(ap, bvv, accO[of]);
      }
    }
    __syncthreads();
  }
  #pragma unroll
  for (int rr = 0; rr < 4; ++rr) {
    float inv = 1.f / lsum[rr];
    int t = qt * 64 + w * 16 + lh * 4 + rr;
    #pragma unroll
    for (int of = 0; of < 8; ++of)
      attn[(size_t)t * WOK + h * DV + of * 16 + l16] = f2bf(accO[of][rr] * inv);
  }
}

extern "C" void kernel_launch(void* const* d_in, const int* in_sizes, int n_in,
                              void* d_out, int out_size, void* d_ws, size_t ws_size,
                              hipStream_t stream) {
  const float* hidden     = (const float*)d_in[0];
  const int*   positions  = (const int*)d_in[1];
  const float* wq_a       = (const float*)d_in[2];
  const float* q_a_ln_w   = (const float*)d_in[3];
  const float* wq_b       = (const float*)d_in[4];
  const float* wkv_a      = (const float*)d_in[5];
  const float* kv_a_ln_w  = (const float*)d_in[6];
  const float* wkv_b      = (const float*)d_in[7];
  const float* wo         = (const float*)d_in[8];
  float* out = (float*)d_out;

  char* p = (char*)d_ws;
  size_t off = 0;
  auto alloc = [&](size_t bytes) -> void* {
    void* r = p + off;
    off += (bytes + 255) & ~(size_t)255;
    return r;
  };
  u16*   h_bf = (u16*)  alloc((size_t)T_SEQ * HID * 2);       // hidden bf16
  u16*   wbuf = (u16*)  alloc((size_t)HID * WOK * 2);         // shared transposed-weight buffer
  u16*   bigh = (u16*)  alloc((size_t)T_SEQ * KVD * 2);       // kvfull bf16, later qfull bf16
  float* sml  = (float*)alloc((size_t)T_SEQ * QL * 4);        // latent f32, later q_lat f32
  u16*   qln  = (u16*)  alloc((size_t)T_SEQ * QL * 2);        // rmsnorm(q_lat) bf16
  u16*   ckv  = (u16*)  alloc((size_t)T_SEQ * KVL * 2);       // rmsnorm(c_kv) bf16
  u16*   Qc   = (u16*)  alloc((size_t)NH * T_SEQ * DQK * 2);  // Q concat, roped, pre-scaled
  u16*   Kc   = (u16*)  alloc((size_t)NH * T_SEQ * DQK * 2);  // K concat
  u16*   Vt   = (u16*)  alloc((size_t)NH * DV * T_SEQ * 2);   // V transposed
  u16*   attn = (u16*)  alloc((size_t)T_SEQ * WOK * 2);       // attention out bf16

  // hidden -> bf16
  k_cvt_bf16<<<(T_SEQ * HID) / (256 * 8), 256, 0, stream>>>(hidden, h_bf, (long long)T_SEQ * HID);

  // ---- KV path ----
  k_transpose_bf16<<<dim3(LATD / 64, HID / 64), 256, 0, stream>>>(wkv_a, wbuf, HID, LATD, 1.0f);
  k_gemm_bt<<<dim3((LATD + 127) / 128, T_SEQ / 128), 256, 0, stream>>>(h_bf, wbuf, sml, T_SEQ, LATD, HID);
  k_rmsnorm_bf16<<<T_SEQ, 256, 0, stream>>>(sml, kv_a_ln_w, ckv, KVL, LATD);
  k_transpose_bf16<<<dim3(KVD / 64, KVL / 64), 256, 0, stream>>>(wkv_b, wbuf, KVL, KVD, 1.0f);
  k_gemm_bt_h<<<dim3(KVD / 128, T_SEQ / 128), 256, 0, stream>>>(ckv, wbuf, bigh, T_SEQ, KVD, KVL);
  k_build_k<<<T_SEQ, 256, 0, stream>>>(bigh, sml, positions, Kc);
  k_build_vt<<<dim3(T_SEQ / 64, 2, NH), 256, 0, stream>>>(bigh, Vt);

  // ---- Q path (reuses bigh/sml after KV consumers are done) ----
  k_transpose_bf16<<<dim3(QL / 64, HID / 64), 256, 0, stream>>>(wq_a, wbuf, HID, QL, 1.0f);
  k_gemm_bt<<<dim3(QL / 128, T_SEQ / 128), 256, 0, stream>>>(h_bf, wbuf, sml, T_SEQ, QL, HID);
  k_rmsnorm_bf16<<<T_SEQ, 256, 0, stream>>>(sml, q_a_ln_w, qln, QL, QL);
  // fold 192^-0.5 score scale into wq_b
  k_transpose_bf16<<<dim3(QD / 64, QL / 64), 256, 0, stream>>>(wq_b, wbuf, QL, QD,
                                                               0.07216878364870322f);
  k_gemm_bt_h<<<dim3(QD / 128, T_SEQ / 128), 256, 0, stream>>>(qln, wbuf, bigh, T_SEQ, QD, QL);
  k_build_q<<<T_SEQ, 256, 0, stream>>>(bigh, positions, Qc);

  // ---- attention ----
  k_mla_attn<<<dim3(T_SEQ / 64, NH), 256, 0, stream>>>(Qc, Kc, Vt, attn);

  // ---- output projection ----
  k_transpose_bf16<<<dim3(HID / 64, WOK / 64), 256, 0, stream>>>(wo, wbuf, WOK, HID, 1.0f);
  k_gemm_bt<<<dim3(HID / 128, T_SEQ / 128), 256, 0, stream>>>(attn, wbuf, out, T_SEQ, HID, WOK);
}

// Round 4
// 676.027 us; speedup vs baseline: 1.5229x; 1.3827x over previous
//
#include <hip/hip_runtime.h>
#include <stdint.h>

#define T_SEQ 2048
#define HID 7168
#define NH 32
#define DN 128
#define DR 64
#define DQK 192
#define DV 128
#define QL 1536
#define KVL 512
#define LATD 576
#define QD 6144
#define KVD 8192
#define WOK 4096
#define NCAT 2112  // QL + LATD merged GEMM width

typedef unsigned short u16;
typedef __bf16 bf16x8 __attribute__((ext_vector_type(8)));
typedef float f32x4 __attribute__((ext_vector_type(4)));

__device__ __forceinline__ u16 f2bf(float f) {
  union { float f; unsigned u; } v; v.f = f;
  unsigned r = v.u + 0x7FFFu + ((v.u >> 16) & 1u);
  return (u16)(r >> 16);
}
__device__ __forceinline__ float bf2f(u16 s) {
  union { unsigned u; float f; } v; v.u = ((unsigned)s) << 16;
  return v.f;
}

__device__ __forceinline__ void gl2lds16(const void* g, void* l) {
  __builtin_amdgcn_global_load_lds((const __attribute__((address_space(1))) void*)g,
                                   (__attribute__((address_space(3))) void*)l, 16, 0, 0);
}

__device__ __forceinline__ f32x4 mfma16(bf16x8 a, bf16x8 b, f32x4 c) {
  return __builtin_amdgcn_mfma_f32_16x16x32_bf16(a, b, c, 0, 0, 0);
}

__device__ __forceinline__ void store_out(float* p, float v) { *p = v; }
__device__ __forceinline__ void store_out(u16* p, float v) { *p = f2bf(v); }

#define FENCE() asm volatile("" ::: "memory")

// ---------------- elementwise f32 -> bf16 ----------------
__global__ __launch_bounds__(256) void k_cvt_bf16(const float* __restrict__ in,
                                                  u16* __restrict__ out, long long n) {
  long long i = ((long long)blockIdx.x * 256 + threadIdx.x) * 8;
  if (i >= n) return;
  const float4* p = (const float4*)(in + i);
  float4 a = p[0], b = p[1];
  union { uint4 v; u16 s[8]; } o;
  o.s[0]=f2bf(a.x); o.s[1]=f2bf(a.y); o.s[2]=f2bf(a.z); o.s[3]=f2bf(a.w);
  o.s[4]=f2bf(b.x); o.s[5]=f2bf(b.y); o.s[6]=f2bf(b.z); o.s[7]=f2bf(b.w);
  *(uint4*)(out + i) = o.v;
}

// ---------------- transpose + convert + scale: in[R][C] f32 -> out[C][R] bf16 ----------------
__global__ __launch_bounds__(256) void k_transpose_bf16(const float* __restrict__ in,
                                                        u16* __restrict__ out, int R, int C,
                                                        float scale) {
  __shared__ float tile[64][65];
  int c0 = blockIdx.x * 64, r0 = blockIdx.y * 64;
  int tx = threadIdx.x & 15, ty = threadIdx.x >> 4;
  #pragma unroll
  for (int i = 0; i < 4; i++) {
    int r = ty + i * 16;
    float4 v = *(const float4*)(in + (size_t)(r0 + r) * C + c0 + tx * 4);
    tile[r][tx*4+0] = v.x; tile[r][tx*4+1] = v.y; tile[r][tx*4+2] = v.z; tile[r][tx*4+3] = v.w;
  }
  __syncthreads();
  #pragma unroll
  for (int i = 0; i < 4; i++) {
    int oc = ty + i * 16;
    union { uint2 v; u16 s[4]; } o;
    #pragma unroll
    for (int j = 0; j < 4; j++) o.s[j] = f2bf(tile[tx*4+j][oc] * scale);
    *(uint2*)(out + (size_t)(c0 + oc) * R + r0 + tx * 4) = o.v;
  }
}

// ---------------- rmsnorm row-wise: f32 in (ld=ldin), bf16 out [n] ----------------
__global__ __launch_bounds__(256) void k_rmsnorm_bf16(const float* __restrict__ x,
                                                      const float* __restrict__ w,
                                                      u16* __restrict__ out, int n, int ldin) {
  int row = blockIdx.x;
  const float* xr = x + (size_t)row * ldin;
  u16* orow = out + (size_t)row * n;
  float ss = 0.f;
  for (int i = threadIdx.x * 4; i < n; i += 1024) {
    float4 v = *(const float4*)(xr + i);
    ss += v.x*v.x + v.y*v.y + v.z*v.z + v.w*v.w;
  }
  #pragma unroll
  for (int off = 32; off > 0; off >>= 1) ss += __shfl_xor(ss, off);
  __shared__ float red[4];
  if ((threadIdx.x & 63) == 0) red[threadIdx.x >> 6] = ss;
  __syncthreads();
  float tot = red[0] + red[1] + red[2] + red[3];
  float rstd = rsqrtf(tot / (float)n + 1e-6f);
  for (int i = threadIdx.x * 4; i < n; i += 1024) {
    float4 v = *(const float4*)(xr + i);
    float4 g = *(const float4*)(w + i);
    union { uint2 u; u16 s[4]; } o;
    o.s[0]=f2bf(v.x*rstd*g.x); o.s[1]=f2bf(v.y*rstd*g.y);
    o.s[2]=f2bf(v.z*rstd*g.z); o.s[3]=f2bf(v.w*rstd*g.w);
    *(uint2*)(orow + i) = o.u;
  }
}

// ---------------- 128^2 GEMM (m97 structure), f32 out, N-guarded ----------------
__global__ __launch_bounds__(256) void k_gemm_bt(const u16* __restrict__ A,
                                                 const u16* __restrict__ Bt,
                                                 float* __restrict__ C,
                                                 int M, int N, int K) {
  __shared__ __attribute__((aligned(16))) u16 As[128 * 32];
  __shared__ __attribute__((aligned(16))) u16 Bs[128 * 32];
  int m0 = blockIdx.y * 128, n0 = blockIdx.x * 128;
  int tid = threadIdx.x;
  int w = tid >> 6, lane = tid & 63, l16 = lane & 15, lh = lane >> 4;
  int wr = (w >> 1) * 64, wc = (w & 1) * 64;
  f32x4 zero = {0.f, 0.f, 0.f, 0.f};
  f32x4 acc[4][4];
  #pragma unroll
  for (int i = 0; i < 4; i++)
    #pragma unroll
    for (int j = 0; j < 4; j++) acc[i][j] = zero;
  int ra = tid >> 2, ca = (tid & 3) * 8;
  const u16* a0 = A + (size_t)(m0 + ra) * K + ca;
  const u16* a1 = A + (size_t)(m0 + ra + 64) * K + ca;
  int rb0 = n0 + ra;      rb0 = rb0 < N ? rb0 : N - 1;
  int rb1 = n0 + ra + 64; rb1 = rb1 < N ? rb1 : N - 1;
  const u16* b0 = Bt + (size_t)rb0 * K + ca;
  const u16* b1 = Bt + (size_t)rb1 * K + ca;
  for (int k0 = 0; k0 < K; k0 += 32) {
    gl2lds16(a0 + k0, &As[tid * 8]);
    gl2lds16(a1 + k0, &As[2048 + tid * 8]);
    gl2lds16(b0 + k0, &Bs[tid * 8]);
    gl2lds16(b1 + k0, &Bs[2048 + tid * 8]);
    __syncthreads();
    bf16x8 af[4], bv[4];
    #pragma unroll
    for (int i = 0; i < 4; i++) af[i] = *(const bf16x8*)&As[(wr + i * 16 + l16) * 32 + lh * 8];
    #pragma unroll
    for (int j = 0; j < 4; j++) bv[j] = *(const bf16x8*)&Bs[(wc + j * 16 + l16) * 32 + lh * 8];
    #pragma unroll
    for (int i = 0; i < 4; i++)
      #pragma unroll
      for (int j = 0; j < 4; j++)
        acc[i][j] = mfma16(af[i], bv[j], acc[i][j]);
    __syncthreads();
  }
  #pragma unroll
  for (int i = 0; i < 4; i++) {
    #pragma unroll
    for (int j = 0; j < 4; j++) {
      int col = n0 + wc + j * 16 + l16;
      if (col < N) {
        #pragma unroll
        for (int r = 0; r < 4; r++) {
          int row = m0 + wr + i * 16 + lh * 4 + r;
          C[(size_t)row * N + col] = acc[i][j][r];
        }
      }
    }
  }
}

// ---------------- 256^2 pipelined GEMM: 3-ring LDS, counted vmcnt, swizzled ----------------
// M%256==0, N%256==0, K%32==0, K/32>=3. A[M][K], Bt[N][K], C[M][N].
// swizzle: within each 16KB area, byte L -> L ^ (((L>>7)&7)<<4)  (involution; key bits
// [9:7] disjoint from flipped bits [6:4])
// vmcnt ledger: each tile stages 4 loads (2 in phase A, 2 in phase B). At end-of-tile t,
// outstanding = tile t+1's 4 + tile t+2's 4 = 8. Next iter reads tile t+1 => retire the
// oldest 4 => s_waitcnt vmcnt(4). (R3 bug: vmcnt(8) was a no-op -> race -> tripwire.)
template <typename OutT>
__global__ __launch_bounds__(512) void k_gemm_bt256(const u16* __restrict__ A,
                                                    const u16* __restrict__ Bt,
                                                    OutT* __restrict__ C,
                                                    int N, int K) {
  __shared__ __attribute__((aligned(16))) u16 lds[3 * 16384];  // 96KB: 3 x (A 16KB | B 16KB)
  const int tid = threadIdx.x;
  const int lane = tid & 63, l16 = lane & 15, lh = lane >> 4;
  const int w = tid >> 6, wm = w >> 2, wn = w & 3;  // 2 x 4 waves
  const int m0 = blockIdx.y * 256, n0 = blockIdx.x * 256;
  const int nt = K >> 5;

  f32x4 acc[8][4];
  #pragma unroll
  for (int i = 0; i < 8; i++)
    #pragma unroll
    for (int j = 0; j < 4; j++) acc[i][j] = f32x4{0.f, 0.f, 0.f, 0.f};

  // staging: thread's linear LDS dest (area-local) P = tid*16; source = swizzle(P)
  const int P = tid * 16;
  const int ls = P ^ (((P >> 7) & 7) << 4);
  const int sr = ls >> 6;            // source row 0..127 within half
  const int sce = (ls & 63) >> 1;    // source col (elements), 16B-aligned
  const u16* gA0 = A + (size_t)(m0 + sr) * K + sce;
  const u16* gA1 = A + (size_t)(m0 + sr + 128) * K + sce;
  const u16* gB0 = Bt + (size_t)(n0 + sr) * K + sce;
  const u16* gB1 = Bt + (size_t)(n0 + sr + 128) * K + sce;
  u16* ldst = &lds[tid * 8];

  for (int pt = 0; pt < 2 && pt < nt; ++pt) {  // prologue: stage tiles 0,1
    gl2lds16(gA0 + pt * 32, ldst + pt * 16384);
    gl2lds16(gA1 + pt * 32, ldst + pt * 16384 + 4096);
    gl2lds16(gB0 + pt * 32, ldst + pt * 16384 + 8192);
    gl2lds16(gB1 + pt * 32, ldst + pt * 16384 + 12288);
  }
  __syncthreads();  // full drain once; tiles 0,1 resident

  int bufr = 0;
  for (int t = 0; t < nt; ++t) {
    const bool more = (t + 2) < nt;
    const int bw = (t + 2) % 3;
    const u16* As = &lds[bufr * 16384];
    const u16* Bs = &lds[bufr * 16384 + 8192];
    bf16x8 afr[4], bfr[4];
    // ---- phase A: B frags + A half0, stage A of t+2 ----
    #pragma unroll
    for (int j = 0; j < 4; ++j) {
      int L = ((wn * 64 + j * 16 + l16) << 6) + (lh << 4);
      bfr[j] = *(const bf16x8*)((const char*)Bs + (L ^ (((L >> 7) & 7) << 4)));
    }
    #pragma unroll
    for (int i = 0; i < 4; ++i) {
      int L = ((wm * 128 + i * 16 + l16) << 6) + (lh << 4);
      afr[i] = *(const bf16x8*)((const char*)As + (L ^ (((L >> 7) & 7) << 4)));
    }
    if (more) {
      gl2lds16(gA0 + (t + 2) * 32, ldst + bw * 16384);
      gl2lds16(gA1 + (t + 2) * 32, ldst + bw * 16384 + 4096);
    }
    FENCE();
    __builtin_amdgcn_s_barrier();
    FENCE();
    __builtin_amdgcn_s_setprio(1);
    #pragma unroll
    for (int i = 0; i < 4; ++i)
      #pragma unroll
      for (int j = 0; j < 4; ++j)
        acc[i][j] = mfma16(afr[i], bfr[j], acc[i][j]);
    __builtin_amdgcn_s_setprio(0);
    FENCE();
    __builtin_amdgcn_s_barrier();
    FENCE();
    // ---- phase B: A half1, stage B of t+2 ----
    #pragma unroll
    for (int i = 0; i < 4; ++i) {
      int L = ((wm * 128 + 64 + i * 16 + l16) << 6) + (lh << 4);
      afr[i] = *(const bf16x8*)((const char*)As + (L ^ (((L >> 7) & 7) << 4)));
    }
    if (more) {
      gl2lds16(gB0 + (t + 2) * 32, ldst + bw * 16384 + 8192);
      gl2lds16(gB1 + (t + 2) * 32, ldst + bw * 16384 + 12288);
    }
    FENCE();
    __builtin_amdgcn_s_barrier();
    FENCE();
    __builtin_amdgcn_s_setprio(1);
    #pragma unroll
    for (int i = 0; i < 4; ++i)
      #pragma unroll
      for (int j = 0; j < 4; ++j)
        acc[4 + i][j] = mfma16(afr[i], bfr[j], acc[4 + i][j]);
    __builtin_amdgcn_s_setprio(0);
    FENCE();
    if (more) asm volatile("s_waitcnt vmcnt(4)" ::: "memory");  // retire tile t+1; t+2 stays in flight
    else      asm volatile("s_waitcnt vmcnt(0)" ::: "memory");  // epilogue drain
    __builtin_amdgcn_s_barrier();
    FENCE();
    bufr = (bufr == 2) ? 0 : bufr + 1;
  }

  #pragma unroll
  for (int hf = 0; hf < 2; ++hf) {
    #pragma unroll
    for (int i = 0; i < 4; ++i) {
      int rbase = m0 + wm * 128 + hf * 64 + i * 16 + lh * 4;
      #pragma unroll
      for (int j = 0; j < 4; ++j) {
        int col = n0 + wn * 64 + j * 16 + l16;
        #pragma unroll
        for (int r = 0; r < 4; ++r)
          store_out(&C[(size_t)(rbase + r) * N + col], acc[hf * 4 + i][j][r]);
      }
    }
  }
}

// ---------------- build Q: qfull[T][6144] bf16 (pre-scaled) -> Qc[NH][T][192] bf16 (rope) ----------------
__global__ __launch_bounds__(256) void k_build_q(const u16* __restrict__ qf,
                                                 const int* __restrict__ pos,
                                                 u16* __restrict__ Qc) {
  int t = blockIdx.x;
  __shared__ float cs[32], sn[32];
  if (threadIdx.x < 32) {
    float inv = expf(-9.2103403719761836f * (float)threadIdx.x / 32.f);
    float ang = (float)pos[t] * inv;
    cs[threadIdx.x] = cosf(ang);
    sn[threadIdx.x] = sinf(ang);
  }
  __syncthreads();
  const u16* qrow = qf + (size_t)t * QD;
  for (int e = threadIdx.x; e < QD; e += 256) {
    int h = e / 192, d = e - h * 192;
    u16 outv;
    if (d < DN) {
      outv = qrow[e];
    } else {
      int dr = d - DN, i = dr >> 1;
      float x1 = bf2f(qrow[h * 192 + DN + 2 * i]), x2 = bf2f(qrow[h * 192 + DN + 2 * i + 1]);
      float v = (dr & 1) ? (x1 * sn[i] + x2 * cs[i]) : (x1 * cs[i] - x2 * sn[i]);
      outv = f2bf(v);
    }
    Qc[((size_t)h * T_SEQ + t) * DQK + d] = outv;
  }
}

// ---------------- build K: kvfull bf16 + k_rope (f32, strided) -> Kc[NH][T][192] bf16 ----------------
__global__ __launch_bounds__(256) void k_build_k(const u16* __restrict__ kvf,
                                                 const float* __restrict__ kr, int krld,
                                                 const int* __restrict__ pos,
                                                 u16* __restrict__ Kc) {
  int t = blockIdx.x;
  __shared__ u16 kro[64];
  if (threadIdx.x < 32) {
    int i = threadIdx.x;
    float inv = expf(-9.2103403719761836f * (float)i / 32.f);
    float ang = (float)pos[t] * inv;
    float c = cosf(ang), s = sinf(ang);
    float x1 = kr[(size_t)t * krld + 2 * i];
    float x2 = kr[(size_t)t * krld + 2 * i + 1];
    kro[2 * i]     = f2bf(x1 * c - x2 * s);
    kro[2 * i + 1] = f2bf(x1 * s + x2 * c);
  }
  __syncthreads();
  const u16* krow = kvf + (size_t)t * KVD;
  for (int e = threadIdx.x; e < NH * DQK; e += 256) {
    int h = e / 192, d = e - h * 192;
    Kc[((size_t)h * T_SEQ + t) * DQK + d] = (d < DN) ? krow[h * 256 + d] : kro[d - DN];
  }
}

// ---------------- build Vt: kvfull bf16 (cols h*256+128..255) -> Vt[NH][128][T] ----------------
__global__ __launch_bounds__(256) void k_build_vt(const u16* __restrict__ kvf,
                                                  u16* __restrict__ Vt) {
  __shared__ unsigned tile[64][65];
  int t0 = blockIdx.x * 64, d0 = blockIdx.y * 64, h = blockIdx.z;
  int tid = threadIdx.x;
  #pragma unroll
  for (int i = 0; i < 2; i++) {
    int r = (tid >> 3) + i * 32;
    int c = (tid & 7) * 8;
    uint4 v = *(const uint4*)(kvf + (size_t)(t0 + r) * KVD + h * 256 + DN + d0 + c);
    const u16* s = (const u16*)&v;
    #pragma unroll
    for (int j = 0; j < 8; j++) tile[r][c + j] = s[j];
  }
  __syncthreads();
  #pragma unroll
  for (int i = 0; i < 2; i++) {
    int d = (tid >> 3) + i * 32;
    int tb = (tid & 7) * 8;
    union { uint4 v; u16 s[8]; } o;
    #pragma unroll
    for (int j = 0; j < 8; j++) o.s[j] = (u16)tile[tb + j][d];
    *(uint4*)(Vt + ((size_t)h * DV + d0 + d) * T_SEQ + t0 + tb) = o.v;
  }
}

// ---------------- flash attention, XOR-swizzled LDS + Q-hoist ----------------
__global__ __launch_bounds__(256) void k_mla_attn(const u16* __restrict__ Qc,
                                                  const u16* __restrict__ Kc,
                                                  const u16* __restrict__ Vt,
                                                  u16* __restrict__ attn) {
  int qt = blockIdx.x, h = blockIdx.y;
  __shared__ __attribute__((aligned(16))) u16 Ks[64 * 192];
  __shared__ __attribute__((aligned(16))) u16 Vs[128 * 64];
  __shared__ __attribute__((aligned(16))) u16 Ps[64 * 64];
  int tid = threadIdx.x, w = tid >> 6, lane = tid & 63, l16 = lane & 15, lh = lane >> 4;
  int swz = (l16 & 7) << 4;

  const char* Qg = (const char*)(Qc + ((size_t)h * T_SEQ + (size_t)qt * 64) * DQK);
  #pragma unroll
  for (int i = 0; i < 6; i++) {
    int L = tid * 16 + i * 4096;
    int row = L / 384;
    gl2lds16(Qg + (L ^ ((row & 7) << 4)), (char*)Ks + L);
  }
  __syncthreads();
  bf16x8 aq[6];
  #pragma unroll
  for (int kf = 0; kf < 6; kf++)
    aq[kf] = *(const bf16x8*)((const char*)Ks + (w * 16 + l16) * 384 + ((kf * 64 + lh * 16) ^ swz));
  __syncthreads();

  f32x4 zero = {0.f, 0.f, 0.f, 0.f};
  f32x4 accO[8];
  #pragma unroll
  for (int i = 0; i < 8; i++) accO[i] = zero;
  float m[4]    = {-3e38f, -3e38f, -3e38f, -3e38f};
  float lsum[4] = {0.f, 0.f, 0.f, 0.f};

  const char* Kb = (const char*)(Kc + (size_t)h * T_SEQ * DQK);
  const char* Vb = (const char*)(Vt + (size_t)h * DV * T_SEQ);

  for (int kt = 0; kt <= qt; ++kt) {
    const char* Kg = Kb + (size_t)kt * 64 * DQK * 2;
    #pragma unroll
    for (int i = 0; i < 6; i++) {
      int L = tid * 16 + i * 4096;
      int row = L / 384;
      gl2lds16(Kg + (L ^ ((row & 7) << 4)), (char*)Ks + L);
    }
    #pragma unroll
    for (int i = 0; i < 4; i++) {
      int L = tid * 16 + i * 4096;
      int row = L >> 7, wb = L & 127;
      gl2lds16(Vb + (size_t)row * (T_SEQ * 2) + (size_t)kt * 128 + (wb ^ ((row & 7) << 4)),
               (char*)Vs + L);
    }
    __syncthreads();

    f32x4 sf[4];
    #pragma unroll
    for (int j = 0; j < 4; j++) sf[j] = zero;
    #pragma unroll
    for (int kf = 0; kf < 6; ++kf) {
      #pragma unroll
      for (int j = 0; j < 4; ++j) {
        bf16x8 bk = *(const bf16x8*)((const char*)Ks + (j * 16 + l16) * 384 +
                                     ((kf * 64 + lh * 16) ^ swz));
        sf[j] = mfma16(aq[kf], bk, sf[j]);
      }
    }
    bool diag = (kt == qt);
    #pragma unroll
    for (int rr = 0; rr < 4; ++rr) {
      int qrow = qt * 64 + w * 16 + lh * 4 + rr;
      float rowm = -3e38f;
      #pragma unroll
      for (int j = 0; j < 4; ++j) {
        float s = sf[j][rr];
        if (diag && (kt * 64 + j * 16 + l16) > qrow) s = -3e38f;
        sf[j][rr] = s;
        rowm = fmaxf(rowm, s);
      }
      rowm = fmaxf(rowm, __shfl_xor(rowm, 1));
      rowm = fmaxf(rowm, __shfl_xor(rowm, 2));
      rowm = fmaxf(rowm, __shfl_xor(rowm, 4));
      rowm = fmaxf(rowm, __shfl_xor(rowm, 8));
      float mnew = fmaxf(m[rr], rowm);
      float sc = __expf(m[rr] - mnew);
      float pj[4];
      float ps = 0.f;
      #pragma unroll
      for (int j = 0; j < 4; ++j) { pj[j] = __expf(sf[j][rr] - mnew); ps += pj[j]; }
      ps += __shfl_xor(ps, 1); ps += __shfl_xor(ps, 2);
      ps += __shfl_xor(ps, 4); ps += __shfl_xor(ps, 8);
      lsum[rr] = lsum[rr] * sc + ps;
      m[rr] = mnew;
      #pragma unroll
      for (int of = 0; of < 8; ++of) accO[of][rr] *= sc;
      int r = w * 16 + lh * 4 + rr;
      int rsw = (r & 7) << 4;
      #pragma unroll
      for (int j = 0; j < 4; ++j)
        *(u16*)((char*)Ps + r * 128 + ((2 * (j * 16 + l16)) ^ rsw)) = f2bf(pj[j]);
    }
    #pragma unroll
    for (int kf = 0; kf < 2; ++kf) {
      bf16x8 ap = *(const bf16x8*)((const char*)Ps + (w * 16 + l16) * 128 +
                                   ((kf * 64 + lh * 16) ^ swz));
      #pragma unroll
      for (int of = 0; of < 8; ++of) {
        bf16x8 bvv = *(const bf16x8*)((const char*)Vs + (of * 16 + l16) * 128 +
                                      ((kf * 64 + lh * 16) ^ swz));
        accO[of] = mfma16(ap, bvv, accO[of]);
      }
    }
    __syncthreads();
  }
  #pragma unroll
  for (int rr = 0; rr < 4; ++rr) {
    float inv = 1.f / lsum[rr];
    int t = qt * 64 + w * 16 + lh * 4 + rr;
    #pragma unroll
    for (int of = 0; of < 8; ++of)
      attn[(size_t)t * WOK + h * DV + of * 16 + l16] = f2bf(accO[of][rr] * inv);
  }
}

extern "C" void kernel_launch(void* const* d_in, const int* in_sizes, int n_in,
                              void* d_out, int out_size, void* d_ws, size_t ws_size,
                              hipStream_t stream) {
  const float* hidden     = (const float*)d_in[0];
  const int*   positions  = (const int*)d_in[1];
  const float* wq_a       = (const float*)d_in[2];
  const float* q_a_ln_w   = (const float*)d_in[3];
  const float* wq_b       = (const float*)d_in[4];
  const float* wkv_a      = (const float*)d_in[5];
  const float* kv_a_ln_w  = (const float*)d_in[6];
  const float* wkv_b      = (const float*)d_in[7];
  const float* wo         = (const float*)d_in[8];
  float* out = (float*)d_out;

  char* p = (char*)d_ws;
  size_t off = 0;
  auto alloc = [&](size_t bytes) -> void* {
    void* r = p + off;
    off += (bytes + 255) & ~(size_t)255;
    return r;
  };
  u16*   h_bf = (u16*)  alloc((size_t)T_SEQ * HID * 2);       // hidden bf16
  u16*   wbuf = (u16*)  alloc((size_t)HID * WOK * 2);         // shared transposed-weight buffer
  u16*   bigh = (u16*)  alloc((size_t)T_SEQ * KVD * 2);       // kvfull bf16, later qfull bf16
  float* cat  = (float*)alloc((size_t)T_SEQ * NCAT * 4);      // [q_lat | c_kv | k_rope] f32
  u16*   qln  = (u16*)  alloc((size_t)T_SEQ * QL * 2);        // rmsnorm(q_lat) bf16
  u16*   ckv  = (u16*)  alloc((size_t)T_SEQ * KVL * 2);       // rmsnorm(c_kv) bf16
  u16*   Qc   = (u16*)  alloc((size_t)NH * T_SEQ * DQK * 2);  // Q concat, roped, pre-scaled
  u16*   Kc   = (u16*)  alloc((size_t)NH * T_SEQ * DQK * 2);  // K concat
  u16*   Vt   = (u16*)  alloc((size_t)NH * DV * T_SEQ * 2);   // V transposed
  u16*   attn = (u16*)  alloc((size_t)T_SEQ * WOK * 2);       // attention out bf16

  // hidden -> bf16
  k_cvt_bf16<<<(T_SEQ * HID) / (256 * 8), 256, 0, stream>>>(hidden, h_bf, (long long)T_SEQ * HID);

  // ---- merged down-projection: [wq_a | wkv_a]^T, N = 1536 + 576 = 2112 ----
  k_transpose_bf16<<<dim3(QL / 64, HID / 64), 256, 0, stream>>>(wq_a, wbuf, HID, QL, 1.0f);
  k_transpose_bf16<<<dim3(LATD / 64, HID / 64), 256, 0, stream>>>(wkv_a, wbuf + (size_t)QL * HID,
                                                                  HID, LATD, 1.0f);
  k_gemm_bt<<<dim3((NCAT + 127) / 128, T_SEQ / 128), 256, 0, stream>>>(h_bf, wbuf, cat,
                                                                       T_SEQ, NCAT, HID);

  // ---- KV path ----
  k_rmsnorm_bf16<<<T_SEQ, 256, 0, stream>>>(cat + QL, kv_a_ln_w, ckv, KVL, NCAT);
  k_transpose_bf16<<<dim3(KVD / 64, KVL / 64), 256, 0, stream>>>(wkv_b, wbuf, KVL, KVD, 1.0f);
  k_gemm_bt256<u16><<<dim3(KVD / 256, T_SEQ / 256), 512, 0, stream>>>(ckv, wbuf, bigh, KVD, KVL);
  k_build_k<<<T_SEQ, 256, 0, stream>>>(bigh, cat + QL + KVL, NCAT, positions, Kc);
  k_build_vt<<<dim3(T_SEQ / 64, 2, NH), 256, 0, stream>>>(bigh, Vt);

  // ---- Q path (bigh reused after build_k/build_vt consumed kvfull) ----
  k_rmsnorm_bf16<<<T_SEQ, 256, 0, stream>>>(cat, q_a_ln_w, qln, QL, NCAT);
  k_transpose_bf16<<<dim3(QD / 64, QL / 64), 256, 0, stream>>>(wq_b, wbuf, QL, QD,
                                                               0.07216878364870322f);
  k_gemm_bt256<u16><<<dim3(QD / 256, T_SEQ / 256), 512, 0, stream>>>(qln, wbuf, bigh, QD, QL);
  k_build_q<<<T_SEQ, 256, 0, stream>>>(bigh, positions, Qc);

  // ---- attention ----
  k_mla_attn<<<dim3(T_SEQ / 64, NH), 256, 0, stream>>>(Qc, Kc, Vt, attn);

  // ---- output projection ----
  k_transpose_bf16<<<dim3(HID / 64, WOK / 64), 256, 0, stream>>>(wo, wbuf, WOK, HID, 1.0f);
  k_gemm_bt256<float><<<dim3(HID / 256, T_SEQ / 256), 512, 0, stream>>>(attn, wbuf, out, HID, WOK);
}